// Round 4
// baseline (323.520 us; speedup 1.0000x reference)
//
#include <hip/hip_runtime.h>
#include <hip/hip_bf16.h>
#include <math.h>

// Problem constants (fixed by the harness)
#define Bq    8
#define Nq    50000
#define CIN   32
#define Sq    9
#define KTOT  288      // Sq*CIN
#define COUT  64
#define MSEG  12500
#define NNZq  50000

#define ROWS  64       // n-rows per block
#define LDK   296      // padded K stride in bf16 elems (592 B, 16B-aligned, conflict-free)

typedef __bf16 bf16x8 __attribute__((ext_vector_type(8)));
typedef float  f32x4  __attribute__((ext_vector_type(4)));

static __device__ __forceinline__ unsigned short f2bf(float f) {
  union { float f; unsigned u; } v; v.f = f;
  unsigned r = v.u + 0x7fffu + ((v.u >> 16) & 1u);   // RNE
  return (unsigned short)(r >> 16);
}

// Kernel 1: fused gather + GEMM(288x64, bf16 MFMA) + bias + ELU -> h (fp32)
// grid: (ceil(N/64), nb), block: 256 (4 waves). h indexed by LOCAL batch (blockIdx.y).
__global__ __launch_bounds__(256) void fused_gather_gemm_elu(
    const float* __restrict__ x, const float* __restrict__ W,
    const float* __restrict__ bias, const int* __restrict__ sidx,
    float* __restrict__ h, int bbase)
{
  __shared__ unsigned short g_lds[ROWS * LDK];   // gathered A rows, bf16
  __shared__ unsigned short wt_lds[COUT * LDK];  // W^T  (wt[c][k]), bf16

  const int tid  = threadIdx.x;
  const int bloc = blockIdx.y;
  const int b    = bbase + bloc;
  const int n0   = blockIdx.x * ROWS;

  // ---- stage W^T into LDS (once per block; W is L2-resident) ----
  #pragma unroll
  for (int it = 0; it < 18; ++it) {
    int i4 = it * 256 + tid;              // [0, 4608) float4s of W
    int k  = i4 >> 4;                     // 16 float4 per k-row of 64 floats
    int c4 = (i4 & 15) << 2;
    float4 w4 = ((const float4*)W)[i4];
    wt_lds[(c4+0)*LDK + k] = f2bf(w4.x);
    wt_lds[(c4+1)*LDK + k] = f2bf(w4.y);
    wt_lds[(c4+2)*LDK + k] = f2bf(w4.z);
    wt_lds[(c4+3)*LDK + k] = f2bf(w4.w);
  }

  // ---- stage gathered x rows: 64 rows x 9 neighbors x 32ch, 8 threads per (row,s) ----
  #pragma unroll
  for (int it = 0; it < 18; ++it) {
    int slot = it * 256 + tid;            // [0, 4608)
    int pair = slot >> 3;                 // (row, s) pair  [0, 576)
    int j    = slot & 7;                  // float4 index within 32 channels
    int r    = pair / 9;
    int s    = pair - r * 9;
    int n    = n0 + r; if (n >= Nq) n = Nq - 1;   // clamp tail (values unused)
    int idx  = sidx[n * Sq + s];
    float4 v = ((const float4*)(x + ((size_t)b * Nq + idx) * CIN))[j];
    ushort4 pk;
    pk.x = f2bf(v.x); pk.y = f2bf(v.y); pk.z = f2bf(v.z); pk.w = f2bf(v.w);
    *(ushort4*)&g_lds[r * LDK + s * 32 + j * 4] = pk;
  }
  __syncthreads();

  // ---- MFMA: each wave computes 16 rows x 64 cols ----
  const int w  = tid >> 6;
  const int l  = tid & 63;
  const int la = l & 15;
  const int kg = l >> 4;

  f32x4 acc[4];
  #pragma unroll
  for (int i = 0; i < 4; ++i) acc[i] = (f32x4){0.f, 0.f, 0.f, 0.f};

  const unsigned short* ap = &g_lds[(w * 16 + la) * LDK + kg * 8];
  const unsigned short* bp = &wt_lds[la * LDK + kg * 8];

  #pragma unroll
  for (int ks = 0; ks < 9; ++ks) {
    bf16x8 a = *(const bf16x8*)(ap + ks * 32);
    #pragma unroll
    for (int ct = 0; ct < 4; ++ct) {
      bf16x8 bb = *(const bf16x8*)(bp + ct * 16 * LDK + ks * 32);
      acc[ct] = __builtin_amdgcn_mfma_f32_16x16x32_bf16(a, bb, acc[ct], 0, 0, 0);
    }
  }

  // ---- epilogue: bias + ELU, store h fp32 ----
  #pragma unroll
  for (int ct = 0; ct < 4; ++ct) {
    int cn = ct * 16 + la;
    float bv = bias[cn];
    #pragma unroll
    for (int r = 0; r < 4; ++r) {
      int n = n0 + w * 16 + kg * 4 + r;     // D: row = 4*(lane>>4)+reg, col = lane&15
      if (n < Nq) {
        float v = acc[ct][r] + bv;
        v = v > 0.f ? v : expm1f(v);        // ELU(alpha=1)
        h[((size_t)bloc * Nq + n) * COUT + cn] = v;
      }
    }
  }
}

// Kernel 2: scatter-add pooling. One wave per (edge, batch); 64 lanes = 64 channels.
__global__ __launch_bounds__(256) void scatter_pool(
    const float* __restrict__ h, const float* __restrict__ value,
    const int* __restrict__ row, const int* __restrict__ col,
    float* __restrict__ out, int bbase, int nb)
{
  int wave = blockIdx.x * 4 + (threadIdx.x >> 6);
  int lane = threadIdx.x & 63;
  if (wave >= NNZq * nb) return;
  int e    = wave / nb;
  int bloc = wave - e * nb;
  int c = col[e];
  int r = row[e];
  float v = value[e];
  float hv = h[((size_t)bloc * Nq + c) * COUT + lane];
  atomicAdd(&out[((size_t)(bbase + bloc) * MSEG + r) * COUT + lane], hv * v);
}

extern "C" void kernel_launch(void* const* d_in, const int* in_sizes, int n_in,
                              void* d_out, int out_size, void* d_ws, size_t ws_size,
                              hipStream_t stream)
{
  const float* x     = (const float*)d_in[0];
  const float* W     = (const float*)d_in[1];
  const float* bias  = (const float*)d_in[2];
  const float* value = (const float*)d_in[3];
  const int*   sidx  = (const int*)d_in[4];
  const int*   row   = (const int*)d_in[5];
  const int*   col   = (const int*)d_in[6];
  float* out = (float*)d_out;
  float* h   = (float*)d_ws;

  hipMemsetAsync(d_out, 0, (size_t)out_size * sizeof(float), stream);

  // h needs B*N*64 fp32 = 102.4 MB; chunk over batches if ws is smaller.
  size_t per_batch = (size_t)Nq * COUT * sizeof(float);
  int nb_max = (int)(ws_size / per_batch);
  if (nb_max > Bq) nb_max = Bq;
  if (nb_max < 1) return;  // cannot run (ws too small)

  int nx = (Nq + ROWS - 1) / ROWS;
  for (int bbase = 0; bbase < Bq; bbase += nb_max) {
    int nb = (Bq - bbase < nb_max) ? (Bq - bbase) : nb_max;
    fused_gather_gemm_elu<<<dim3(nx, nb), 256, 0, stream>>>(x, W, bias, sidx, h, bbase);
    int waves = NNZq * nb;
    scatter_pool<<<(waves + 3) / 4, 256, 0, stream>>>(h, value, row, col, out, bbase, nb);
  }
}

// Round 5
// 311.709 us; speedup vs baseline: 1.0379x; 1.0379x over previous
//
#include <hip/hip_runtime.h>
#include <hip/hip_bf16.h>
#include <math.h>

// Problem constants (fixed by the harness)
#define Bq    8
#define Nq    50000
#define CIN   32
#define Sq    9
#define COUT  64
#define MSEG  12500
#define NNZq  50000
#define KSTEPS 9          // 288 / 32

#define WT_BYTES 65536    // reserve 64KB at front of ws for W^T (uses 36,864B)

typedef __bf16 bf16x8 __attribute__((ext_vector_type(8)));
typedef float  f32x4  __attribute__((ext_vector_type(4)));

static __device__ __forceinline__ unsigned short f2bf(float f) {
  union { float f; unsigned u; } v; v.f = f;
  unsigned r = v.u + 0x7fffu + ((v.u >> 16) & 1u);   // RNE
  return (unsigned short)(r >> 16);
}

// Prep: W[288][64] f32 -> WT[64][288] bf16 (tiny, once per call; L1/L2-resident after)
__global__ __launch_bounds__(256) void prep_wt(const float* __restrict__ W,
                                               unsigned short* __restrict__ WT)
{
  int t = blockIdx.x * 256 + threadIdx.x;     // 288*64 = 18432 elems
  if (t >= 288 * 64) return;
  int c = t & 63;
  int k = t >> 6;
  WT[c * 288 + k] = f2bf(W[k * 64 + c]);      // coalesced read; scattered 2B write (tiny)
}

// Kernel 1: fused gather + GEMM(288x64, bf16 MFMA) + bias + ELU -> h (fp32)
// NO LDS: each lane gathers its A-fragment (2x float4) straight from x;
// B-fragments stream from L1/L2-hot WT. grid 1-D: bloc = bid & (nb-1) -> XCD/batch
// L2 affinity when nb==8. h layout: [n][bloc][c] (for contiguous scatter reads).
__global__ __launch_bounds__(256, 4) void fused_gather_gemm_elu(
    const float* __restrict__ x, const unsigned short* __restrict__ WT,
    const float* __restrict__ bias, const int* __restrict__ sidx,
    float* __restrict__ h, int bbase, int nb, int lgnb)
{
  const int tid  = threadIdx.x;
  const int bid  = blockIdx.x;
  const int bloc = bid & (nb - 1);
  const int n0   = (bid >> lgnb) * 64;
  const int b    = bbase + bloc;

  const int w  = tid >> 6;
  const int l  = tid & 63;
  const int la = l & 15;
  const int kg = l >> 4;

  int nrow   = n0 + w * 16 + la;
  int nclamp = nrow < Nq ? nrow : Nq - 1;

  // 9 spiral indices for this lane's row (lanes la=0..15 read consecutive 36B rows)
  int idxs[KSTEPS];
  #pragma unroll
  for (int s = 0; s < KSTEPS; ++s) idxs[s] = sidx[nclamp * Sq + s];

  const float* xb = x + (size_t)b * Nq * CIN + kg * 8;
  const __bf16* wb = (const __bf16*)WT + la * 288 + kg * 8;

  f32x4 acc[4];
  #pragma unroll
  for (int i = 0; i < 4; ++i) acc[i] = (f32x4){0.f, 0.f, 0.f, 0.f};

  #pragma unroll
  for (int ks = 0; ks < KSTEPS; ++ks) {
    const float* ap = xb + (size_t)idxs[ks] * CIN;   // 32B for this lane's k-slice
    float4 a0 = ((const float4*)ap)[0];
    float4 a1 = ((const float4*)ap)[1];
    bf16x8 a;
    a[0] = (__bf16)a0.x; a[1] = (__bf16)a0.y; a[2] = (__bf16)a0.z; a[3] = (__bf16)a0.w;
    a[4] = (__bf16)a1.x; a[5] = (__bf16)a1.y; a[6] = (__bf16)a1.z; a[7] = (__bf16)a1.w;
    #pragma unroll
    for (int ct = 0; ct < 4; ++ct) {
      bf16x8 bb = *(const bf16x8*)(wb + ct * 16 * 288 + ks * 32);
      acc[ct] = __builtin_amdgcn_mfma_f32_16x16x32_bf16(a, bb, acc[ct], 0, 0, 0);
    }
  }

  // epilogue: bias + ELU (fast exp), store h[n][bloc][c]
  #pragma unroll
  for (int ct = 0; ct < 4; ++ct) {
    int cn = ct * 16 + la;
    float bv = bias[cn];
    #pragma unroll
    for (int r = 0; r < 4; ++r) {
      int n = n0 + w * 16 + kg * 4 + r;     // D: row = 4*(lane>>4)+reg, col = lane&15
      if (n < Nq) {
        float v = acc[ct][r] + bv;
        v = v > 0.f ? v : (__expf(v) - 1.0f);  // ELU(alpha=1)
        h[((size_t)n * nb + bloc) * COUT + cn] = v;
      }
    }
  }
}

// Kernel 2: scatter-add pooling. Thread i -> (e, bloc, c), c fastest:
// reads h[col[e]][*][*] as nb*256B CONTIGUOUS; atomics to out[b][row][c].
__global__ __launch_bounds__(256) void scatter_pool(
    const float* __restrict__ h, const float* __restrict__ value,
    const int* __restrict__ row, const int* __restrict__ col,
    float* __restrict__ out, int bbase, int nb, int lgnb)
{
  int i    = blockIdx.x * 256 + threadIdx.x;
  int c    = i & 63;
  int rem  = i >> 6;
  int bloc = rem & (nb - 1);
  int e    = rem >> lgnb;
  if (e >= NNZq) return;
  int   cc = col[e];
  int   rr = row[e];
  float v  = value[e];
  float hv = h[((size_t)cc * nb + bloc) * COUT + c];
  atomicAdd(&out[((size_t)(bbase + bloc) * MSEG + rr) * COUT + c], hv * v);
}

extern "C" void kernel_launch(void* const* d_in, const int* in_sizes, int n_in,
                              void* d_out, int out_size, void* d_ws, size_t ws_size,
                              hipStream_t stream)
{
  const float* x     = (const float*)d_in[0];
  const float* W     = (const float*)d_in[1];
  const float* bias  = (const float*)d_in[2];
  const float* value = (const float*)d_in[3];
  const int*   sidx  = (const int*)d_in[4];
  const int*   row   = (const int*)d_in[5];
  const int*   col   = (const int*)d_in[6];
  float* out = (float*)d_out;

  unsigned short* WT = (unsigned short*)d_ws;
  float* h = (float*)((char*)d_ws + WT_BYTES);

  if (ws_size < WT_BYTES + (size_t)Nq * COUT * sizeof(float)) return;
  size_t per_batch = (size_t)Nq * COUT * sizeof(float);   // 12.8 MB
  int nb_max = (int)((ws_size - WT_BYTES) / per_batch);
  int nb, lgnb;
  if      (nb_max >= 8) { nb = 8; lgnb = 3; }
  else if (nb_max >= 4) { nb = 4; lgnb = 2; }
  else if (nb_max >= 2) { nb = 2; lgnb = 1; }
  else                  { nb = 1; lgnb = 0; }

  hipMemsetAsync(d_out, 0, (size_t)out_size * sizeof(float), stream);
  prep_wt<<<(288 * 64 + 255) / 256, 256, 0, stream>>>(W, WT);

  int nx = (Nq + 63) / 64;                                // 782
  for (int bbase = 0; bbase < Bq; bbase += nb) {
    fused_gather_gemm_elu<<<nx * nb, 256, 0, stream>>>(x, WT, bias, sidx, h,
                                                       bbase, nb, lgnb);
    int threads = NNZq * COUT * nb;
    scatter_pool<<<(threads + 255) / 256, 256, 0, stream>>>(h, value, row, col, out,
                                                            bbase, nb, lgnb);
  }
}